// Round 4
// baseline (109.854 us; speedup 1.0000x reference)
//
#include <hip/hip_runtime.h>
#include <math.h>

typedef _Float16 h2 __attribute__((ext_vector_type(2)));
typedef unsigned int u32;

#define T_LEN 1024
#define L_LEN 64
#define BIGV  1e30f
#define COLU4 3   // uint4 slots per staged column (2 data + 1 pad)

__device__ __forceinline__ h2 as_h2(u32 u) { union { u32 u; h2 h; } x; x.u = u; return x.h; }
// wave_shr:1 — lane i gets src(lane i-1); lane 0 keeps `old` (bound_ctrl=false).
__device__ __forceinline__ u32 dpp_shr1(u32 oldv, u32 src) {
  return (u32)__builtin_amdgcn_update_dpp((int)oldv, (int)src, 0x138, 0xF, 0xF, false);
}

__global__ __launch_bounds__(256) void dtw_wavefront(
    const float* __restrict__ x,      // (16, 16, 1024)
    const float* __restrict__ patts,  // (64, 16, 64)
    float* __restrict__ out,          // (16, 64, 64, 64)
    float w) {
  __shared__ uint4 xs4[T_LEN * COLU4];   // 48 KiB f16-packed columns
  __shared__ float x2a[T_LEN];           // 4 KiB f32 ||x_t||^2

  const int tid  = threadIdx.x;
  const int lane = tid & 63;
  const int wv   = tid >> 6;
  const int b    = blockIdx.x >> 4;
  const int p    = (blockIdx.x & 15) * 4 + wv;

  // ---- stage x[b]: f16-pack columns + f32 x2 ----
  const float* xb = x + b * (16 * T_LEN);
  for (int t = tid; t < T_LEN; t += 256) {
    float v[16]; float s2 = 0.f;
    #pragma unroll
    for (int dd = 0; dd < 16; ++dd) { float f = xb[dd * T_LEN + t]; v[dd] = f; s2 = fmaf(f, f, s2); }
    u32 pk[8];
    #pragma unroll
    for (int j = 0; j < 8; ++j) {
      union { _Float16 hh[2]; u32 u; } c;
      c.hh[0] = (_Float16)v[2*j]; c.hh[1] = (_Float16)v[2*j+1];
      pk[j] = c.u;
    }
    xs4[t*COLU4]   = make_uint4(pk[0], pk[1], pk[2], pk[3]);
    xs4[t*COLU4+1] = make_uint4(pk[4], pk[5], pk[6], pk[7]);
    x2a[t] = s2;
  }
  __syncthreads();

  // ---- lane-resident pattern column p[:, lane] ----
  const float* pp = patts + p * (16 * L_LEN);
  h2 pv[8]; float p2 = 0.f;
  #pragma unroll
  for (int j = 0; j < 8; ++j) {
    float f0 = pp[(2*j) * L_LEN + lane];
    float f1 = pp[(2*j+1) * L_LEN + lane];
    p2 = fmaf(f0, f0, fmaf(f1, f1, p2));
    h2 h; h.x = (_Float16)f0; h.y = (_Float16)f1;
    pv[j] = h;
  }
  const float nhp2 = -0.5f * p2;
  const int bigbits = __float_as_int(BIGV);

  float* op = out + ((b * 64 + p) * 64 + lane) * 64;

  float prev = BIGV, shA = BIGV, shB = BIGV;
  uint4 da, db; float sx2;                       // lane-resident column (t = s - lane)
  uint4 A0,B0,A1,B1,A2,B2,A3,B3; float X0,X1,X2v,X3v;  // broadcast prefetch, 4 deep

  #define COL_LOAD(A,B,X,c) do { A = xs4[(c)*COLU4]; B = xs4[(c)*COLU4+1]; X = x2a[(c)]; } while (0)

  COL_LOAD(da, db, sx2, 0);      // lane 0's column for s=0 (others masked garbage)
  COL_LOAD(A0,B0,X0, 1);
  COL_LOAD(A1,B1,X1, 2);
  COL_LOAD(A2,B2,X2v, 3);
  COL_LOAD(A3,B3,X3v, 4);

  #define DOT() \
      float c0_ = __builtin_amdgcn_fdot2(as_h2(da.x), pv[0], nhp2, false); \
      float c1_ = __builtin_amdgcn_fdot2(as_h2(da.y), pv[1], 0.f,  false); \
      c0_ = __builtin_amdgcn_fdot2(as_h2(da.z), pv[2], c0_, false); \
      c1_ = __builtin_amdgcn_fdot2(as_h2(da.w), pv[3], c1_, false); \
      c0_ = __builtin_amdgcn_fdot2(as_h2(db.x), pv[4], c0_, false); \
      c1_ = __builtin_amdgcn_fdot2(as_h2(db.y), pv[5], c1_, false); \
      c0_ = __builtin_amdgcn_fdot2(as_h2(db.z), pv[6], c0_, false); \
      c1_ = __builtin_amdgcn_fdot2(as_h2(db.w), pv[7], c1_, false); \
      float sq_ = fmaf(-2.f, c0_ + c1_, sx2); \
      float dist = __builtin_amdgcn_sqrtf(fmaxf(sq_, 1e-12f))

  // Shift all lane-resident state down one lane; fresh column enters at lane 0
  // via the tied `old` operand (buffer reg dies here -> single v_mov_b32_dpp each).
  #define SHIFTS(AA,BB,XX,curv) do { \
      da.x = dpp_shr1(AA.x, da.x); da.y = dpp_shr1(AA.y, da.y); \
      da.z = dpp_shr1(AA.z, da.z); da.w = dpp_shr1(AA.w, da.w); \
      db.x = dpp_shr1(BB.x, db.x); db.y = dpp_shr1(BB.y, db.y); \
      db.z = dpp_shr1(BB.z, db.z); db.w = dpp_shr1(BB.w, db.w); \
      sx2  = __int_as_float((int)dpp_shr1((u32)__float_as_int(XX), (u32)__float_as_int(sx2))); \
      shB = shA; \
      shA = __int_as_float((int)dpp_shr1((u32)bigbits, (u32)__float_as_int(curv))); \
      prev = (curv); } while (0)

  // ===== prologue: s in [0,64), BIG-check + t>=0 mask =====
  #pragma unroll 1
  for (int s = 0; s < 64; s += 4) {
    #define PSTEP(J, AA,BB,XX) do { \
      const int t_ = s + (J) - lane; \
      DOT(); \
      float m_  = fminf(fminf(prev, shA), shB); \
      float ms_ = (m_ >= 0.5e30f) ? 0.f : m_; \
      float val_ = fmaf(w, ms_, dist); \
      float cur_ = (t_ >= 0) ? val_ : BIGV; \
      SHIFTS(AA,BB,XX, cur_); \
      COL_LOAD(AA,BB,XX, s + (J) + 5); \
    } while (0)
    PSTEP(0, A0,B0,X0);
    PSTEP(1, A1,B1,X1);
    PSTEP(2, A2,B2,X2v);
    PSTEP(3, A3,B3,X3v);
    #undef PSTEP
  }

  // ===== main: s in [64,960), no boundary cases =====
  #pragma unroll 1
  for (int s = 64; s < 960; s += 4) {
    #define MSTEP(J, AA,BB,XX) do { \
      DOT(); \
      float m_ = fminf(fminf(prev, shA), shB); \
      float cur_ = fmaf(w, m_, dist); \
      SHIFTS(AA,BB,XX, cur_); \
      COL_LOAD(AA,BB,XX, s + (J) + 5); \
    } while (0)
    MSTEP(0, A0,B0,X0);
    MSTEP(1, A1,B1,X1);
    MSTEP(2, A2,B2,X2v);
    MSTEP(3, A3,B3,X3v);
    #undef MSTEP
  }

  // ===== epilogue: s in [960,1088), t<T mask + stores =====
  #pragma unroll 1
  for (int s = 960; s < 1088; s += 4) {
    #define ESTEP(J, AA,BB,XX) do { \
      const int t_ = s + (J) - lane; \
      DOT(); \
      float m_ = fminf(fminf(prev, shA), shB); \
      float val_ = fmaf(w, m_, dist); \
      float cur_ = (t_ < T_LEN) ? val_ : BIGV; \
      if ((u32)(t_ - 960) < 64u) op[t_ - 960] = val_; \
      SHIFTS(AA,BB,XX, cur_); \
      int c_ = s + (J) + 5; c_ = c_ > (T_LEN-1) ? (T_LEN-1) : c_; \
      COL_LOAD(AA,BB,XX, c_); \
    } while (0)
    ESTEP(0, A0,B0,X0);
    ESTEP(1, A1,B1,X1);
    ESTEP(2, A2,B2,X2v);
    ESTEP(3, A3,B3,X3v);
    #undef ESTEP
  }
}

extern "C" void kernel_launch(void* const* d_in, const int* in_sizes, int n_in,
                              void* d_out, int out_size, void* d_ws, size_t ws_size,
                              hipStream_t stream) {
  const float* x     = (const float*)d_in[0];
  const float* patts = (const float*)d_in[1];
  float* out         = (float*)d_out;
  const float w = (float)exp(log(0.1) / 64.0);
  dim3 grid(256), block(256);
  hipLaunchKernelGGL(dtw_wavefront, grid, block, 0, stream, x, patts, out, w);
}

// Round 5
// 59.250 us; speedup vs baseline: 1.8541x; 1.8541x over previous
//
#include <hip/hip_runtime.h>
#include <math.h>

typedef _Float16 half8 __attribute__((ext_vector_type(8)));
typedef float f32x4 __attribute__((ext_vector_type(4)));
typedef unsigned int u32;
typedef unsigned long long u64;
typedef unsigned short u16;

#define BIGV 1e30f

__device__ __forceinline__ u32 dpp_shr1(u32 oldv, u32 src) {
  return (u32)__builtin_amdgcn_update_dpp((int)oldv, (int)src, 0x138, 0xF, 0xF, false);
}
__device__ __forceinline__ float h2f(u32 bits) {
  union { u16 u; _Float16 h; } c; c.u = (u16)bits; return (float)c.h;
}
__device__ __forceinline__ u16 f2h(float f) {
  union { _Float16 h; u16 u; } c; c.h = (_Float16)f; return c.u;
}

// One wave per (b,p). Producer: MFMA dist tiles (16 t-cols) -> f16 diagonal ring
// ring[l][(t+l)&127]. Consumer: wavefront step s: lane=l consumes ring[l][s],
// uniform aligned b64 read every 4 steps (8 ahead). Serial chain: min3+fma+dpp.
__global__ __launch_bounds__(256) void dtw_mfma(
    const float* __restrict__ x,      // (16,16,1024)
    const float* __restrict__ patts,  // (64,16,64)
    float* __restrict__ out,          // (16,64,64,64)
    float w) {
  __shared__ uint4 xsq[2050];          // f16 x cols (32B each) + zero block at 2048
  __shared__ float x2a[1024];          // ||x_t||^2
  __shared__ u16   ring[4][64 * 132];  // per-wave dist ring, row stride 132 halves
  __shared__ float obuf[4][64 * 16];   // per-wave output transpose buffer

  const int tid = threadIdx.x, lane = tid & 63, wv = tid >> 6;
  const int b = blockIdx.x >> 4, p = (blockIdx.x & 15) * 4 + wv;
  const int le = lane & 15, kq = lane >> 4;

  // ---- stage x: f16-packed columns + f32 norms ----
  const float* xb = x + b * (16 * 1024);
  for (int t = tid; t < 1024; t += 256) {
    float v[16]; float s2 = 0.f;
#pragma unroll
    for (int d = 0; d < 16; ++d) { float f = xb[d * 1024 + t]; v[d] = f; s2 = fmaf(f, f, s2); }
    u32 pk[8];
#pragma unroll
    for (int j = 0; j < 8; ++j) {
      union { _Float16 h[2]; u32 u; } c;
      c.h[0] = (_Float16)v[2 * j]; c.h[1] = (_Float16)v[2 * j + 1];
      pk[j] = c.u;
    }
    xsq[2 * t]     = make_uint4(pk[0], pk[1], pk[2], pk[3]);
    xsq[2 * t + 1] = make_uint4(pk[4], pk[5], pk[6], pk[7]);
    x2a[t] = s2;
  }
  if (tid == 0) { xsq[2048] = make_uint4(0, 0, 0, 0); xsq[2049] = make_uint4(0, 0, 0, 0); }

  // ---- B fragments: p scaled by -2 (so MFMA gives -2*x.p), plus p2[l] per nb ----
  half8 bf[4]; float p2c[4];
  {
    const float* pp = patts + p * (16 * 64);
#pragma unroll
    for (int nb = 0; nb < 4; ++nb) {
      float pv[8]; float part = 0.f;
#pragma unroll
      for (int j = 0; j < 8; ++j) {
        float f = (kq < 2) ? pp[(8 * kq + j) * 64 + nb * 16 + le] : 0.f;
        pv[j] = f; part = fmaf(f, f, part);
      }
      part += __shfl_xor(part, 16, 64);
      part += __shfl_xor(part, 32, 64);
      p2c[nb] = part;
      half8 h;
#pragma unroll
      for (int j = 0; j < 8; ++j) h[j] = (_Float16)(-2.f * pv[j]);
      bf[nb] = h;
    }
  }
  __syncthreads();

  u16* rg = ring[wv];
  float* obf = obuf[wv];

#define PRODUCE(T0) do { \
    int aidx_ = (kq < 2) ? (2 * ((T0) + le) + kq) : 2048; \
    union { uint4 q; half8 h; } au_; au_.q = xsq[aidx_]; \
    f32x4 x2q_ = *(const f32x4*)&x2a[(T0) + 4 * kq]; \
    _Pragma("unroll") \
    for (int nb_ = 0; nb_ < 4; ++nb_) { \
      f32x4 c_ = {0.f, 0.f, 0.f, 0.f}; \
      c_ = __builtin_amdgcn_mfma_f32_16x16x32_f16(au_.h, bf[nb_], c_, 0, 0, 0); \
      int l_ = nb_ * 16 + le; \
      u16* rp_ = rg + l_ * 132; \
      int dg_ = (T0) + 4 * kq + l_; \
      _Pragma("unroll") \
      for (int i_ = 0; i_ < 4; ++i_) { \
        float sq_ = c_[i_] + x2q_[i_] + p2c[nb_]; \
        float d_ = __builtin_amdgcn_sqrtf(fmaxf(sq_, 1e-12f)); \
        rp_[(dg_ + i_) & 127] = f2h(d_); \
      } \
    } \
  } while (0)

  // pre-produce tiles 0..2, make writes visible, prime consumer FIFO
  PRODUCE(0); PRODUCE(16); PRODUCE(32);
  __syncthreads();

  const u16* rc = rg + lane * 132;
  u64 fs0 = *(const u64*)&rc[0];
  u64 fs1 = *(const u64*)&rc[4];
  u64 fs2 = *(const u64*)&rc[8];
  u64 fs3 = 0;

  float prev = BIGV, shA = BIGV, shB = BIGV;
  const int bigbits = __float_as_int(BIGV);
  float* oprow = out + ((b * 64 + p) * 64 + lane) * 64;
  float* obw = obf + lane * 16;
  int nextq = 240;

#define SHIFT(curv) do { shB = shA; \
    shA = __int_as_float((int)dpp_shr1((u32)bigbits, (u32)__float_as_int(curv))); \
    prev = (curv); } while (0)

#define STEP_PRO(S, DIST) do { \
    float m_ = fminf(fminf(prev, shA), shB); \
    float ms_ = (m_ >= 0.5e30f) ? 0.f : m_; \
    float val_ = fmaf(w, ms_, (DIST)); \
    int t_ = (S) - lane; \
    float cur_ = (t_ >= 0) ? val_ : BIGV; \
    SHIFT(cur_); \
  } while (0)

#define STEP_MAIN(S, DIST) do { \
    float m_ = fminf(fminf(prev, shA), shB); \
    float cur_ = fmaf(w, m_, (DIST)); \
    SHIFT(cur_); \
  } while (0)

#define STEP_EPI(S, DIST) do { \
    float m_ = fminf(fminf(prev, shA), shB); \
    float val_ = fmaf(w, m_, (DIST)); \
    int t_ = (S) - lane; \
    float cur_ = (t_ <= 1023) ? val_ : BIGV; \
    if ((u32)(t_ - 960) < 64u) obw[t_ & 15] = val_; \
    SHIFT(cur_); \
  } while (0)

#define QUAD(S0, QQ, CONS, REFILL, STEPM) do { \
    u64 cq_ = CONS; \
    REFILL = *(const u64*)&rc[((S0) + 12 + 4 * (QQ)) & 127]; \
    STEPM((S0) + 4 * (QQ) + 0, h2f((u32)cq_ & 0xffffu)); \
    STEPM((S0) + 4 * (QQ) + 1, h2f(((u32)cq_ >> 16))); \
    STEPM((S0) + 4 * (QQ) + 2, h2f((u32)(cq_ >> 32) & 0xffffu)); \
    STEPM((S0) + 4 * (QQ) + 3, h2f((u32)(cq_ >> 48))); \
  } while (0)

#define RB(SQ) do { \
    if (nextq < 256 && 4 * nextq + 3 <= (SQ) - 1 - lane - 4) { \
      float4 v_ = *(const float4*)&obf[lane * 16 + ((nextq & 3) << 2)]; \
      *(float4*)(oprow + (nextq << 2) - 960) = v_; ++nextq; \
    } \
  } while (0)

#pragma unroll 1
  for (int blk = 0; blk < 4; ++blk) {       // s in [0,64): boundary masks + BIG check
    PRODUCE(16 * (blk + 3));
    int s0 = 16 * blk;
    QUAD(s0, 0, fs0, fs3, STEP_PRO); QUAD(s0, 1, fs1, fs0, STEP_PRO);
    QUAD(s0, 2, fs2, fs1, STEP_PRO); QUAD(s0, 3, fs3, fs2, STEP_PRO);
  }
#pragma unroll 1
  for (int blk = 4; blk < 60; ++blk) {      // lean middle
    PRODUCE(16 * (blk + 3));
    int s0 = 16 * blk;
    QUAD(s0, 0, fs0, fs3, STEP_MAIN); QUAD(s0, 1, fs1, fs0, STEP_MAIN);
    QUAD(s0, 2, fs2, fs1, STEP_MAIN); QUAD(s0, 3, fs3, fs2, STEP_MAIN);
  }
#pragma unroll 1
  for (int blk = 60; blk < 68; ++blk) {     // stores + t<=1023 mask
    if (blk == 60) PRODUCE(16 * 63);
    int s0 = 16 * blk;
    RB(s0 + 0);  QUAD(s0, 0, fs0, fs3, STEP_EPI);
    RB(s0 + 4);  QUAD(s0, 1, fs1, fs0, STEP_EPI);
    RB(s0 + 8);  QUAD(s0, 2, fs2, fs1, STEP_EPI);
    RB(s0 + 12); QUAD(s0, 3, fs3, fs2, STEP_EPI);
  }
  // drain remaining output quads
#pragma unroll
  for (int r = 0; r < 4; ++r) {
    if (nextq < 256) {
      float4 v_ = *(const float4*)&obf[lane * 16 + ((nextq & 3) << 2)];
      *(float4*)(oprow + (nextq << 2) - 960) = v_; ++nextq;
    }
  }
}

extern "C" void kernel_launch(void* const* d_in, const int* in_sizes, int n_in,
                              void* d_out, int out_size, void* d_ws, size_t ws_size,
                              hipStream_t stream) {
  const float* x     = (const float*)d_in[0];
  const float* patts = (const float*)d_in[1];
  float* out         = (float*)d_out;
  const float w = (float)exp(log(0.1) / 64.0);
  dim3 grid(256), block(256);
  hipLaunchKernelGGL(dtw_mfma, grid, block, 0, stream, x, patts, out, w);
}

// Round 7
// 55.518 us; speedup vs baseline: 1.9787x; 1.0672x over previous
//
#include <hip/hip_runtime.h>
#include <math.h>

typedef _Float16 half8 __attribute__((ext_vector_type(8)));
typedef float    f32x4 __attribute__((ext_vector_type(4)));
typedef unsigned int u32;
typedef unsigned long long u64;
typedef unsigned short u16;

#define BIGV 1e30f

__device__ __forceinline__ u32 dpp_shr1(u32 oldv, u32 src) {
  return (u32)__builtin_amdgcn_update_dpp((int)oldv, (int)src, 0x138, 0xF, 0xF, false);
}
__device__ __forceinline__ float cvtlo(u32 v) {
  union { u16 u; _Float16 h; } c; c.u = (u16)v; return (float)c.h;
}
__device__ __forceinline__ u16 f2h(float f) {
  union { _Float16 h; u16 u; } c; c.h = (_Float16)f; return c.u;
}
__device__ __forceinline__ u32 pkrtz(float a, float b) {
  auto v = __builtin_amdgcn_cvt_pkrtz(a, b);           // v_cvt_pkrtz_f16_f32
  union { decltype(v) h; u32 u; } c; c.h = v; return c.u;
}
__device__ __forceinline__ u32 funnel16(u32 hi, u32 lo, u32 sh) {
  return (u32)(((((u64)hi) << 32) | (u64)lo) >> sh);   // v_alignbit
}

// One wave per (b,p). Producer: 4x mfma_16x16x32_f16 per 16-t tile, norms folded
// into K-slots 16/17, dists packed (cvt_pkrtz) -> 4x ds_write_b64 into t-major
// f16 ring ring[l][t&127] (288B row stride incl. 16-halfword mirror).
// Consumer: 5x ds_read_b64 aligned quads/tile, in-register funnel re-align,
// serial DP chain = min3 -> fma -> dpp(wave_shr:1).
__global__ __launch_bounds__(256) void dtw_mfma2(
    const float* __restrict__ x,      // (16,16,1024)
    const float* __restrict__ patts,  // (64,16,64)
    float* __restrict__ out,          // (16,64,64,64)
    float w) {
  __shared__ uint4 xsq[2050];        // f16-packed x columns + zero block @2048
  __shared__ uint2 ring2[4 * 2304];  // per-wave ring: 64 rows x 288B
  __shared__ float obuf[4 * 1024];   // per-wave output transpose buffer
  __shared__ u16   x2h16[1024];      // ||x_t||^2 as f16

  const int tid = threadIdx.x, lane = tid & 63, wv = tid >> 6;
  const int b = blockIdx.x >> 4, p = (blockIdx.x & 15) * 4 + wv;
  const int le = lane & 15, kq = lane >> 4;

  // ---- stage x ----
  const float* xb = x + b * (16 * 1024);
  for (int t = tid; t < 1024; t += 256) {
    float v[16]; float s2 = 0.f;
#pragma unroll
    for (int d = 0; d < 16; ++d) { float f = xb[d * 1024 + t]; v[d] = f; s2 = fmaf(f, f, s2); }
    u32 pk[8];
#pragma unroll
    for (int j = 0; j < 8; ++j) pk[j] = (u32)f2h(v[2 * j]) | ((u32)f2h(v[2 * j + 1]) << 16);
    xsq[2 * t]     = make_uint4(pk[0], pk[1], pk[2], pk[3]);
    xsq[2 * t + 1] = make_uint4(pk[4], pk[5], pk[6], pk[7]);
    x2h16[t] = f2h(s2);
  }
  if (tid == 0) { xsq[2048] = make_uint4(0, 0, 0, 0); xsq[2049] = make_uint4(0, 0, 0, 0); }

  // ---- B fragments: -2p in k=0..15; k16=1, k17=p2 (norm fold) ----
  half8 bf[4];
  {
    const float* pp = patts + p * (16 * 64);
#pragma unroll
    for (int nb = 0; nb < 4; ++nb) {
      float pv[8]; float part = 0.f;
#pragma unroll
      for (int j = 0; j < 8; ++j) {
        float f = (kq < 2) ? pp[(8 * kq + j) * 64 + nb * 16 + le] : 0.f;
        pv[j] = f; part = fmaf(f, f, part);
      }
      part += __shfl_xor(part, 16, 64);
      part += __shfl_xor(part, 32, 64);
      u32 wd0 = pkrtz(-2.f * pv[0], -2.f * pv[1]);
      u32 wd1 = pkrtz(-2.f * pv[2], -2.f * pv[3]);
      u32 wd2 = pkrtz(-2.f * pv[4], -2.f * pv[5]);
      u32 wd3 = pkrtz(-2.f * pv[6], -2.f * pv[7]);
      if (kq == 2) { wd0 = 0x3C00u | ((u32)f2h(part) << 16); wd1 = 0; wd2 = 0; wd3 = 0; }
      union { uint4 q; half8 h; } bu; bu.q = make_uint4(wd0, wd1, wd2, wd3);
      bf[nb] = bu.h;
    }
  }
  __syncthreads();

  // ---- producer / consumer state ----
  int colp = 8 * kq;                              // byte col of (2*T0+8kq)&255
  const int wpbase = wv * 2304 + 36 * le;         // uint2 index of producer row base
  int colc = (((0 - lane) >> 2) << 3) & 255;      // byte col of lane's first aligned quad
  const int ph = (0 - lane) & 3;
  const u32 shv = (u32)((ph & 1) * 16);
  const bool sel2 = (ph & 2) != 0;
  const int rcbase = wv * 2304 + 36 * lane;

  float prev = BIGV, shA = BIGV, shB = BIGV;
  const int bigbits = __float_as_int(BIGV);
  float* obf = obuf + wv * 1024;
  float* obw = obf + lane * 16;
  float* oprow = out + ((b * 64 + p) * 64 + lane) * 64;
  int nextq = 240;

#define PRODUCE(T0) { \
    int aidx_ = (kq < 2) ? (2 * ((T0) + le) + kq) : 2048; \
    uint4 aq_ = xsq[aidx_]; \
    u32 x2b_ = (u32)x2h16[(T0) + le]; \
    aq_.x = (kq == 2) ? (x2b_ | 0x3C000000u) : aq_.x; \
    union { uint4 q; half8 h; } au_; au_.q = aq_; \
    int wb_ = wpbase + (colp >> 3); \
    bool mir_ = colp < 32; \
    _Pragma("unroll") \
    for (int nb_ = 0; nb_ < 4; ++nb_) { \
      f32x4 c_ = {0.f, 0.f, 0.f, 0.f}; \
      c_ = __builtin_amdgcn_mfma_f32_16x16x32_f16(au_.h, bf[nb_], c_, 0, 0, 0); \
      float d0_ = __builtin_amdgcn_sqrtf(fmaxf(c_[0], 1e-12f)); \
      float d1_ = __builtin_amdgcn_sqrtf(fmaxf(c_[1], 1e-12f)); \
      float d2_ = __builtin_amdgcn_sqrtf(fmaxf(c_[2], 1e-12f)); \
      float d3_ = __builtin_amdgcn_sqrtf(fmaxf(c_[3], 1e-12f)); \
      uint2 st_; st_.x = pkrtz(d0_, d1_); st_.y = pkrtz(d2_, d3_); \
      ring2[wb_ + 576 * nb_] = st_; \
      if (mir_) ring2[wb_ + 576 * nb_ + 32] = st_; \
    } \
    colp = (colp + 32) & 255; }

#define SHIFT(curv) { shB = shA; \
    shA = __int_as_float((int)dpp_shr1((u32)bigbits, (u32)__float_as_int(curv))); \
    prev = (curv); }

#define STEP_PRO(S, D) { float dist_ = (D); \
    float m_ = fminf(fminf(prev, shA), shB); \
    float ms_ = (m_ >= 0.5e30f) ? 0.f : m_; \
    float val_ = fmaf(w, ms_, dist_); \
    int t_ = (S) - lane; float cur_ = (t_ >= 0) ? val_ : BIGV; \
    SHIFT(cur_); }

#define STEP_MAIN(S, D) { float dist_ = (D); \
    float m_ = fminf(fminf(prev, shA), shB); \
    float cur_ = fmaf(w, m_, dist_); \
    SHIFT(cur_); }

#define STEP_EPI(S, D) { float dist_ = (D); \
    float m_ = fminf(fminf(prev, shA), shB); \
    float val_ = fmaf(w, m_, dist_); \
    int t_ = (S) - lane; float cur_ = (t_ <= 1023) ? val_ : BIGV; \
    if ((u32)(t_ - 960) < 64u) obw[t_ & 15] = val_; \
    SHIFT(cur_); }

#define FLUSHQ(SQ) { \
    if (nextq < 256 && 4 * nextq + 3 <= (SQ) - 1 - lane - 4) { \
      float4 v_ = *(const float4*)&obf[lane * 16 + ((nextq & 3) << 2)]; \
      *(float4*)(oprow + (nextq << 2) - 960) = v_; ++nextq; \
    } }

#define EXTRACT8(Q0, Q1, Q2, Q3, Q4) \
    u32 W0_ = sel2 ? Q0.y : Q0.x, W1_ = sel2 ? Q1.x : Q0.y, \
        W2_ = sel2 ? Q1.y : Q1.x, W3_ = sel2 ? Q2.x : Q1.y, \
        W4_ = sel2 ? Q2.y : Q2.x, W5_ = sel2 ? Q3.x : Q2.y, \
        W6_ = sel2 ? Q3.y : Q3.x, W7_ = sel2 ? Q4.x : Q3.y, \
        W8_ = sel2 ? Q4.y : Q4.x; \
    u32 A0 = funnel16(W1_, W0_, shv), A1 = funnel16(W2_, W1_, shv), \
        A2 = funnel16(W3_, W2_, shv), A3 = funnel16(W4_, W3_, shv), \
        A4 = funnel16(W5_, W4_, shv), A5 = funnel16(W6_, W5_, shv), \
        A6 = funnel16(W7_, W6_, shv), A7 = funnel16(W8_, W7_, shv);

#define S16(S0, STP) \
    STP((S0)+0,  cvtlo(A0)); STP((S0)+1,  cvtlo(A0 >> 16)); \
    STP((S0)+2,  cvtlo(A1)); STP((S0)+3,  cvtlo(A1 >> 16)); \
    STP((S0)+4,  cvtlo(A2)); STP((S0)+5,  cvtlo(A2 >> 16)); \
    STP((S0)+6,  cvtlo(A3)); STP((S0)+7,  cvtlo(A3 >> 16)); \
    STP((S0)+8,  cvtlo(A4)); STP((S0)+9,  cvtlo(A4 >> 16)); \
    STP((S0)+10, cvtlo(A5)); STP((S0)+11, cvtlo(A5 >> 16)); \
    STP((S0)+12, cvtlo(A6)); STP((S0)+13, cvtlo(A6 >> 16)); \
    STP((S0)+14, cvtlo(A7)); STP((S0)+15, cvtlo(A7 >> 16));

#define SET_PRO(S0)  S16(S0, STEP_PRO)
#define SET_MAIN(S0) S16(S0, STEP_MAIN)
#define SET_EPI(S0) \
    FLUSHQ((S0)+0);  STEP_EPI((S0)+0,  cvtlo(A0)); STEP_EPI((S0)+1,  cvtlo(A0 >> 16)); \
                     STEP_EPI((S0)+2,  cvtlo(A1)); STEP_EPI((S0)+3,  cvtlo(A1 >> 16)); \
    FLUSHQ((S0)+4);  STEP_EPI((S0)+4,  cvtlo(A2)); STEP_EPI((S0)+5,  cvtlo(A2 >> 16)); \
                     STEP_EPI((S0)+6,  cvtlo(A3)); STEP_EPI((S0)+7,  cvtlo(A3 >> 16)); \
    FLUSHQ((S0)+8);  STEP_EPI((S0)+8,  cvtlo(A4)); STEP_EPI((S0)+9,  cvtlo(A4 >> 16)); \
                     STEP_EPI((S0)+10, cvtlo(A5)); STEP_EPI((S0)+11, cvtlo(A5 >> 16)); \
    FLUSHQ((S0)+12); STEP_EPI((S0)+12, cvtlo(A6)); STEP_EPI((S0)+13, cvtlo(A6 >> 16)); \
                     STEP_EPI((S0)+14, cvtlo(A7)); STEP_EPI((S0)+15, cvtlo(A7 >> 16));

#define TILE_BODY(QA0,QA1,QA2,QA3,QA4, QB0,QB1,QB2,QB3,QB4, S0, DOPROD, T0V, STEPSET) { \
    int ci_ = rcbase + (colc >> 3); \
    QB0 = ring2[ci_];     QB1 = ring2[ci_ + 1]; QB2 = ring2[ci_ + 2]; \
    QB3 = ring2[ci_ + 3]; QB4 = ring2[ci_ + 4]; \
    colc = (colc + 32) & 255; \
    if (DOPROD) { PRODUCE(T0V); } \
    EXTRACT8(QA0, QA1, QA2, QA3, QA4); \
    STEPSET(S0); }

  // ---- prime: produce tiles 0..2, load consumer tile 0 ----
  PRODUCE(0); PRODUCE(16); PRODUCE(32);
  uint2 q0, q1, q2, q3, q4, r0, r1, r2, r3, r4;
  {
    int ci_ = rcbase + (colc >> 3);
    q0 = ring2[ci_];     q1 = ring2[ci_ + 1]; q2 = ring2[ci_ + 2];
    q3 = ring2[ci_ + 3]; q4 = ring2[ci_ + 4];
    colc = (colc + 32) & 255;
  }

  // ---- region A: s in [0,64), BIG-check + t>=0 mask ----
#pragma unroll 1
  for (int blk = 0; blk < 4; blk += 2) {
    int s0 = 16 * blk;
    TILE_BODY(q0,q1,q2,q3,q4, r0,r1,r2,r3,r4, s0,      1, 16*blk+48, SET_PRO);
    TILE_BODY(r0,r1,r2,r3,r4, q0,q1,q2,q3,q4, s0+16,   1, 16*blk+64, SET_PRO);
  }
  // ---- region B: s in [64,960), lean ----
#pragma unroll 1
  for (int blk = 4; blk < 60; blk += 2) {
    int s0 = 16 * blk;
    TILE_BODY(q0,q1,q2,q3,q4, r0,r1,r2,r3,r4, s0,      1, 16*blk+48, SET_MAIN);
    TILE_BODY(r0,r1,r2,r3,r4, q0,q1,q2,q3,q4, s0+16,   1, 16*blk+64, SET_MAIN);
  }
  // ---- region C: s in [960,1088), stores + t<=1023 mask ----
#pragma unroll 1
  for (int blk = 60; blk < 68; blk += 2) {
    int s0 = 16 * blk;
    TILE_BODY(q0,q1,q2,q3,q4, r0,r1,r2,r3,r4, s0,      blk == 60, 1008, SET_EPI);
    TILE_BODY(r0,r1,r2,r3,r4, q0,q1,q2,q3,q4, s0+16,   0,         0,    SET_EPI);
  }
  // drain remaining output quads
#pragma unroll
  for (int rr = 0; rr < 4; ++rr) {
    if (nextq < 256) {
      float4 v_ = *(const float4*)&obf[lane * 16 + ((nextq & 3) << 2)];
      *(float4*)(oprow + (nextq << 2) - 960) = v_; ++nextq;
    }
  }
}

extern "C" void kernel_launch(void* const* d_in, const int* in_sizes, int n_in,
                              void* d_out, int out_size, void* d_ws, size_t ws_size,
                              hipStream_t stream) {
  const float* x     = (const float*)d_in[0];
  const float* patts = (const float*)d_in[1];
  float* out         = (float*)d_out;
  const float w = (float)exp(log(0.1) / 64.0);
  dim3 grid(256), block(256);
  hipLaunchKernelGGL(dtw_mfma2, grid, block, 0, stream, x, patts, out, w);
}

// Round 8
// 43.753 us; speedup vs baseline: 2.5108x; 1.2689x over previous
//
#include <hip/hip_runtime.h>
#include <math.h>

typedef _Float16 half8 __attribute__((ext_vector_type(8)));
typedef _Float16 h2 __attribute__((ext_vector_type(2)));
typedef float    f32x4 __attribute__((ext_vector_type(4)));
typedef unsigned int u32;
typedef unsigned long long u64;
typedef unsigned short u16;

#define BIGV 1e30f

__device__ __forceinline__ u32 dpp_shr1(u32 oldv, u32 src) {
  return (u32)__builtin_amdgcn_update_dpp((int)oldv, (int)src, 0x138, 0xF, 0xF, false);
}
__device__ __forceinline__ float cvtlo(u32 v) {
  union { u16 u; _Float16 h; } c; c.u = (u16)v; return (float)c.h;
}
__device__ __forceinline__ u16 f2h(float f) {
  union { _Float16 h; u16 u; } c; c.h = (_Float16)f; return c.u;
}
__device__ __forceinline__ u32 pkrtz(float a, float b) {
  auto v = __builtin_amdgcn_cvt_pkrtz(a, b);
  union { decltype(v) h; u32 u; } c; c.h = v; return c.u;
}
__device__ __forceinline__ u32 funnel16(u32 hi, u32 lo, u32 sh) {
  return (u32)(((((u64)hi) << 32) | (u64)lo) >> sh);   // v_alignbit
}
__device__ __forceinline__ h2 as_h2(u32 u) { union { u32 u; h2 h; } x; x.u = u; return x.h; }

// Producer/consumer wave specialization. Block = 512 thr = 8 waves for 4 (b,p)
// pairs: waves 0-3 produce MFMA dist tiles into per-pair f16 rings (t-major,
// 288B row stride); waves 4-7 run the serial DP chain only. __syncthreads()
// every 2 tiles; producer leads by 2-3 tiles (fits the 128-t ring window).
__global__ __launch_bounds__(512) void dtw_pc(
    const float* __restrict__ x,      // (16,16,1024)
    const float* __restrict__ patts,  // (64,16,64)
    float* __restrict__ out,          // (16,64,64,64)
    float w) {
  __shared__ uint4 xsq[2050];        // f16-packed x columns + zero block @2048
  __shared__ uint2 ring2[4 * 2304];  // per-pair ring: 64 rows x 288B
  __shared__ float obuf[4 * 1024];   // per-pair output staging
  __shared__ u16   x2h16[1024];      // ||x_t||^2 as f16

  const int tid = threadIdx.x, lane = tid & 63, wv = tid >> 6;
  const int b = blockIdx.x >> 4, pg = blockIdx.x & 15;
  const int role = wv >> 2, pr = wv & 3;
  const int p = pg * 4 + pr;
  const int le = lane & 15, kq = lane >> 4;

  // ---- stage x: coalesced global loads -> f16 LDS (hw index t*16+d) ----
  {
    const float* xb = x + b * (16 * 1024);
    u16* xh = (u16*)xsq;
    for (int idx = tid; idx < 16384; idx += 512) {
      int d = idx >> 10, t = idx & 1023;
      xh[t * 16 + d] = f2h(xb[idx]);
    }
    if (tid == 0) { xsq[2048] = make_uint4(0,0,0,0); xsq[2049] = make_uint4(0,0,0,0); }
    __syncthreads();   // B-stage: xsq visible (x2 pass reads it back)
    for (int t = tid; t < 1024; t += 512) {
      uint4 a0 = xsq[2 * t], a1 = xsq[2 * t + 1];
      float s2 = __builtin_amdgcn_fdot2(as_h2(a0.x), as_h2(a0.x), 0.f, false);
      s2 = __builtin_amdgcn_fdot2(as_h2(a0.y), as_h2(a0.y), s2, false);
      s2 = __builtin_amdgcn_fdot2(as_h2(a0.z), as_h2(a0.z), s2, false);
      s2 = __builtin_amdgcn_fdot2(as_h2(a0.w), as_h2(a0.w), s2, false);
      s2 = __builtin_amdgcn_fdot2(as_h2(a1.x), as_h2(a1.x), s2, false);
      s2 = __builtin_amdgcn_fdot2(as_h2(a1.y), as_h2(a1.y), s2, false);
      s2 = __builtin_amdgcn_fdot2(as_h2(a1.z), as_h2(a1.z), s2, false);
      s2 = __builtin_amdgcn_fdot2(as_h2(a1.w), as_h2(a1.w), s2, false);
      x2h16[t] = f2h(s2);
    }
  }
  __syncthreads();   // B0: staging complete

  if (role == 0) {
    // ================= PRODUCER =================
    half8 bf[4];
    {
      const float* pp = patts + p * (16 * 64);
#pragma unroll
      for (int nb = 0; nb < 4; ++nb) {
        float pv[8]; float part = 0.f;
#pragma unroll
        for (int j = 0; j < 8; ++j) {
          float f = (kq < 2) ? pp[(8 * kq + j) * 64 + nb * 16 + le] : 0.f;
          pv[j] = f; part = fmaf(f, f, part);
        }
        part += __shfl_xor(part, 16, 64);
        part += __shfl_xor(part, 32, 64);
        u32 wd0 = pkrtz(-2.f * pv[0], -2.f * pv[1]);
        u32 wd1 = pkrtz(-2.f * pv[2], -2.f * pv[3]);
        u32 wd2 = pkrtz(-2.f * pv[4], -2.f * pv[5]);
        u32 wd3 = pkrtz(-2.f * pv[6], -2.f * pv[7]);
        if (kq == 2) { wd0 = 0x3C00u | ((u32)f2h(part) << 16); wd1 = 0; wd2 = 0; wd3 = 0; }
        union { uint4 q; half8 h; } bu; bu.q = make_uint4(wd0, wd1, wd2, wd3);
        bf[nb] = bu.h;
      }
    }
    int colp = 8 * kq;
    const int wpbase = pr * 2304 + 36 * le;

#define PRODUCE(T0) { \
    int aidx_ = (kq < 2) ? (2 * ((T0) + le) + kq) : 2048; \
    uint4 aq_ = xsq[aidx_]; \
    u32 x2b_ = (u32)x2h16[(T0) + le]; \
    aq_.x = (kq == 2) ? (x2b_ | 0x3C000000u) : aq_.x; \
    union { uint4 q; half8 h; } au_; au_.q = aq_; \
    int wb_ = wpbase + (colp >> 3); \
    bool mir_ = colp < 32; \
    _Pragma("unroll") \
    for (int nb_ = 0; nb_ < 4; ++nb_) { \
      f32x4 c_ = {0.f, 0.f, 0.f, 0.f}; \
      c_ = __builtin_amdgcn_mfma_f32_16x16x32_f16(au_.h, bf[nb_], c_, 0, 0, 0); \
      float d0_ = __builtin_amdgcn_sqrtf(fmaxf(c_[0], 1e-12f)); \
      float d1_ = __builtin_amdgcn_sqrtf(fmaxf(c_[1], 1e-12f)); \
      float d2_ = __builtin_amdgcn_sqrtf(fmaxf(c_[2], 1e-12f)); \
      float d3_ = __builtin_amdgcn_sqrtf(fmaxf(c_[3], 1e-12f)); \
      uint2 st_; st_.x = pkrtz(d0_, d1_); st_.y = pkrtz(d2_, d3_); \
      ring2[wb_ + 576 * nb_] = st_; \
      if (mir_) ring2[wb_ + 576 * nb_ + 32] = st_; \
    } \
    colp = (colp + 32) & 255; }

    PRODUCE(0); PRODUCE(16);
    __syncthreads();   // B1: tiles 0,1 ready
#pragma unroll 1
    for (int k = 0; k < 31; ++k) {       // produce tiles 2k+2, 2k+3 (t<=1023)
      PRODUCE(32 * k + 32);
      PRODUCE(32 * k + 48);
      __syncthreads();
    }
    __syncthreads(); __syncthreads(); __syncthreads();   // phases 31..33

  } else {
    // ================= CONSUMER =================
    const int rcbase = pr * 2304 + 36 * lane;
    int colc = (((0 - lane) >> 2) << 3) & 255;
    const int ph = (0 - lane) & 3;
    const u32 shv = (u32)((ph & 1) * 16);
    const bool sel2 = (ph & 2) != 0;
    float prev = BIGV, shA = BIGV, shB = BIGV;
    const int bigbits = __float_as_int(BIGV);
    float* obf = obuf + pr * 1024;
    float* obw = obf + lane * 16;
    float* oprow = out + ((b * 64 + p) * 64 + lane) * 64;
    int nextq = 240;

#define LOADQ(Q0,Q1,Q2,Q3,Q4) { int ci_ = rcbase + (colc >> 3); \
    Q0 = ring2[ci_];     Q1 = ring2[ci_ + 1]; Q2 = ring2[ci_ + 2]; \
    Q3 = ring2[ci_ + 3]; Q4 = ring2[ci_ + 4]; \
    colc = (colc + 32) & 255; }

#define SHIFT(curv) { shB = shA; \
    shA = __int_as_float((int)dpp_shr1((u32)bigbits, (u32)__float_as_int(curv))); \
    prev = (curv); }

#define STEP_PRO(S, D) { float dist_ = (D); \
    float m_ = fminf(fminf(prev, shA), shB); \
    float ms_ = (m_ >= 0.5e30f) ? 0.f : m_; \
    float val_ = fmaf(w, ms_, dist_); \
    int t_ = (S) - lane; float cur_ = (t_ >= 0) ? val_ : BIGV; \
    SHIFT(cur_); }

#define STEP_MAIN(S, D) { float dist_ = (D); \
    float m_ = fminf(fminf(prev, shA), shB); \
    float cur_ = fmaf(w, m_, dist_); \
    SHIFT(cur_); }

#define STEP_EPI(S, D) { float dist_ = (D); \
    float m_ = fminf(fminf(prev, shA), shB); \
    float val_ = fmaf(w, m_, dist_); \
    int t_ = (S) - lane; float cur_ = (t_ <= 1023) ? val_ : BIGV; \
    if ((u32)(t_ - 960) < 64u) obw[t_ & 15] = val_; \
    SHIFT(cur_); }

#define FLUSHQ(SQ) { \
    if (nextq < 256 && 4 * nextq + 3 <= (SQ) - 1 - lane - 4) { \
      float4 v_ = *(const float4*)&obf[lane * 16 + ((nextq & 3) << 2)]; \
      *(float4*)(oprow + (nextq << 2) - 960) = v_; ++nextq; \
    } }

#define EXTRACT8(Q0, Q1, Q2, Q3, Q4) \
    u32 W0_ = sel2 ? Q0.y : Q0.x, W1_ = sel2 ? Q1.x : Q0.y, \
        W2_ = sel2 ? Q1.y : Q1.x, W3_ = sel2 ? Q2.x : Q1.y, \
        W4_ = sel2 ? Q2.y : Q2.x, W5_ = sel2 ? Q3.x : Q2.y, \
        W6_ = sel2 ? Q3.y : Q3.x, W7_ = sel2 ? Q4.x : Q3.y, \
        W8_ = sel2 ? Q4.y : Q4.x; \
    u32 A0 = funnel16(W1_, W0_, shv), A1 = funnel16(W2_, W1_, shv), \
        A2 = funnel16(W3_, W2_, shv), A3 = funnel16(W4_, W3_, shv), \
        A4 = funnel16(W5_, W4_, shv), A5 = funnel16(W6_, W5_, shv), \
        A6 = funnel16(W7_, W6_, shv), A7 = funnel16(W8_, W7_, shv);

#define S16(S0, STP) \
    STP((S0)+0,  cvtlo(A0)); STP((S0)+1,  cvtlo(A0 >> 16)); \
    STP((S0)+2,  cvtlo(A1)); STP((S0)+3,  cvtlo(A1 >> 16)); \
    STP((S0)+4,  cvtlo(A2)); STP((S0)+5,  cvtlo(A2 >> 16)); \
    STP((S0)+6,  cvtlo(A3)); STP((S0)+7,  cvtlo(A3 >> 16)); \
    STP((S0)+8,  cvtlo(A4)); STP((S0)+9,  cvtlo(A4 >> 16)); \
    STP((S0)+10, cvtlo(A5)); STP((S0)+11, cvtlo(A5 >> 16)); \
    STP((S0)+12, cvtlo(A6)); STP((S0)+13, cvtlo(A6 >> 16)); \
    STP((S0)+14, cvtlo(A7)); STP((S0)+15, cvtlo(A7 >> 16));

#define SET_EPI(S0) \
    FLUSHQ((S0)+0);  STEP_EPI((S0)+0,  cvtlo(A0)); STEP_EPI((S0)+1,  cvtlo(A0 >> 16)); \
                     STEP_EPI((S0)+2,  cvtlo(A1)); STEP_EPI((S0)+3,  cvtlo(A1 >> 16)); \
    FLUSHQ((S0)+4);  STEP_EPI((S0)+4,  cvtlo(A2)); STEP_EPI((S0)+5,  cvtlo(A2 >> 16)); \
                     STEP_EPI((S0)+6,  cvtlo(A3)); STEP_EPI((S0)+7,  cvtlo(A3 >> 16)); \
    FLUSHQ((S0)+8);  STEP_EPI((S0)+8,  cvtlo(A4)); STEP_EPI((S0)+9,  cvtlo(A4 >> 16)); \
                     STEP_EPI((S0)+10, cvtlo(A5)); STEP_EPI((S0)+11, cvtlo(A5 >> 16)); \
    FLUSHQ((S0)+12); STEP_EPI((S0)+12, cvtlo(A6)); STEP_EPI((S0)+13, cvtlo(A6 >> 16)); \
                     STEP_EPI((S0)+14, cvtlo(A7)); STEP_EPI((S0)+15, cvtlo(A7 >> 16));

    __syncthreads();   // B1: tiles 0,1 ready
#pragma unroll 1
    for (int k = 0; k < 2; ++k) {            // s in [0,64): BIG-check + t>=0 mask
      uint2 q0,q1,q2,q3,q4, r0,r1,r2,r3,r4;
      LOADQ(q0,q1,q2,q3,q4);
      LOADQ(r0,r1,r2,r3,r4);
      int s0 = 32 * k;
      { EXTRACT8(q0,q1,q2,q3,q4); S16(s0, STEP_PRO); }
      { EXTRACT8(r0,r1,r2,r3,r4); S16(s0 + 16, STEP_PRO); }
      __syncthreads();
    }
#pragma unroll 1
    for (int k = 2; k < 30; ++k) {           // s in [64,960): lean
      uint2 q0,q1,q2,q3,q4, r0,r1,r2,r3,r4;
      LOADQ(q0,q1,q2,q3,q4);
      LOADQ(r0,r1,r2,r3,r4);
      int s0 = 32 * k;
      { EXTRACT8(q0,q1,q2,q3,q4); S16(s0, STEP_MAIN); }
      { EXTRACT8(r0,r1,r2,r3,r4); S16(s0 + 16, STEP_MAIN); }
      __syncthreads();
    }
#pragma unroll 1
    for (int k = 30; k < 34; ++k) {          // s in [960,1088): stores + mask
      uint2 q0,q1,q2,q3,q4, r0,r1,r2,r3,r4;
      LOADQ(q0,q1,q2,q3,q4);
      LOADQ(r0,r1,r2,r3,r4);
      int s0 = 32 * k;
      { EXTRACT8(q0,q1,q2,q3,q4); SET_EPI(s0); }
      { EXTRACT8(r0,r1,r2,r3,r4); SET_EPI(s0 + 16); }
      __syncthreads();
    }
    // drain remaining output quads
#pragma unroll
    for (int rr = 0; rr < 4; ++rr) {
      if (nextq < 256) {
        float4 v_ = *(const float4*)&obf[lane * 16 + ((nextq & 3) << 2)];
        *(float4*)(oprow + (nextq << 2) - 960) = v_; ++nextq;
      }
    }
  }
}

extern "C" void kernel_launch(void* const* d_in, const int* in_sizes, int n_in,
                              void* d_out, int out_size, void* d_ws, size_t ws_size,
                              hipStream_t stream) {
  const float* x     = (const float*)d_in[0];
  const float* patts = (const float*)d_in[1];
  float* out         = (float*)d_out;
  const float w = (float)exp(log(0.1) / 64.0);
  dim3 grid(256), block(512);
  hipLaunchKernelGGL(dtw_pc, grid, block, 0, stream, x, patts, out, w);
}